// Round 3
// baseline (2184.118 us; speedup 1.0000x reference)
//
#include <hip/hip_runtime.h>
#include <hip/hip_bf16.h>
#include <cstddef>

// MCSHeteroGNN: 2-layer hetero GAT.
// Node types: idle(100k), quasi(100k), task(50k). 5 edge types x 500k edges.
// Float tensor dtype (f32 vs bf16) is DETECTED at runtime (k_detect) and all
// float params are widened to f32 in ws (k_convert). Edges are int32.
//
// ws layout (bytes), total ~137.2 MB:
//   flag   int      @ 0
//   params f32      @ 256         (~7.55 MB: all 16 float inputs widened)
//   h      bf16     @ 7,600,000   (32,000,000)  [idle|quasi|task]
//   hs     bf16     @ 39,600,000  (12,800,000)
//   als    f32      @ 52,400,000  ( 1,600,000)
//   ald    f32      @ 54,000,000  ( 1,600,000)
//   num0-2 f32      @ 55,600,000 / 81,200,000 / 106,800,000 (25,600,000 each)
//   den0-2 f32      @ 132,400,000 / 134,000,000 / 135,600,000 (1,600,000 each)

static constexpr int NI = 100000, NQ = 100000, NT = 50000, NE = 500000;

__device__ __forceinline__ float b2f(__hip_bfloat16 x) { return __bfloat162float(x); }
__device__ __forceinline__ __hip_bfloat16 f2b(float x) { return __float2bfloat16(x); }

// ---- dtype sniff: even halfwords of an f32 randn buffer have random
// "exponent" bits; bf16 randn halfwords have sane exponents (~[113,129]).
__global__ void k_detect(const unsigned short* __restrict__ x, int* __restrict__ flag)
{
    __shared__ int sh[256];
    int tid = threadIdx.x;
    int sane = 0;
    for (int i = tid * 2; i < 2048; i += 512) {   // 1024 even halfword samples
        unsigned short h = x[i];
        int e = (h >> 7) & 0xFF;
        if (h == 0 || (e >= 100 && e <= 140)) sane++;
    }
    sh[tid] = sane;
    __syncthreads();
    for (int s = 128; s; s >>= 1) { if (tid < s) sh[tid] += sh[tid + s]; __syncthreads(); }
    if (tid == 0) *flag = (sh[0] < 512) ? 1 : 0;   // 1 = buffers are f32
}

struct ConvArgs { const void* src[16]; float* dst[16]; int n[16]; };

__global__ void k_convert(ConvArgs a, const int* __restrict__ flag)
{
    int t = blockIdx.y;
    int i = blockIdx.x * 256 + threadIdx.x;
    if (i >= a.n[t]) return;
    float v = (*flag) ? ((const float*)a.src[t])[i]
                      : b2f(((const __hip_bfloat16*)a.src[t])[i]);
    a.dst[t][i] = v;
}

// ---------------- input projection: h = relu(x @ W + b) --------------------
__global__ void k_inproj(const float* __restrict__ x, int N, int F,
                         const float* __restrict__ W,   // [F,64]
                         const float* __restrict__ b,   // [64]
                         __hip_bfloat16* __restrict__ h)
{
    __shared__ float Wsh[8 * 64];
    __shared__ float bsh[64];
    int tid = threadIdx.x;
    for (int i = tid; i < F * 64; i += 256) Wsh[i] = W[i];
    if (tid < 64) bsh[tid] = b[tid];
    __syncthreads();
    int col = tid & 63;
    int n = blockIdx.x * 4 + (tid >> 6);
    if (n >= N) return;
    const float* xr = x + (size_t)n * F;
    float acc = bsh[col];
    for (int k = 0; k < F; ++k) acc += xr[k] * Wsh[k * 64 + col];
    h[(size_t)n * 64 + col] = f2b(fmaxf(acc, 0.f));
}

// ------------- hs = h_src @ Wsrc (bf16 out) + al_s = <hs, a_src> -----------
__global__ void k_transform(const __hip_bfloat16* __restrict__ hsrc, int N,
                            const float* __restrict__ W,     // [64,64]
                            const float* __restrict__ avec,  // [4,16]
                            __hip_bfloat16* __restrict__ hs, // [N,64]
                            float* __restrict__ al)          // [N,4]
{
    __shared__ float Wsh[64 * 64];
    __shared__ float hsh[4][64];
    __shared__ float ash[64];
    int tid = threadIdx.x;
    for (int i = tid; i < 4096; i += 256) Wsh[i] = W[i];
    if (tid < 64) ash[tid] = avec[tid];
    int nl = tid >> 6, col = tid & 63;
    int n = blockIdx.x * 4 + nl;
    hsh[nl][col] = (n < N) ? b2f(hsrc[(size_t)n * 64 + col]) : 0.f;
    __syncthreads();
    if (n >= N) return;
    float acc = 0.f;
#pragma unroll
    for (int k = 0; k < 64; ++k) acc += hsh[nl][k] * Wsh[k * 64 + col];
    hs[(size_t)n * 64 + col] = f2b(acc);
    float p = acc * ash[col];
    p += __shfl_xor(p, 8, 16);
    p += __shfl_xor(p, 4, 16);
    p += __shfl_xor(p, 2, 16);
    p += __shfl_xor(p, 1, 16);
    if ((col & 15) == 0) al[(size_t)n * 4 + (col >> 4)] = p;
}

// ---------- al_d = h_dst @ Weff, Weff[k,h] = sum_c Wdst[k,h*16+c]*a[h,c] ----
__global__ void k_ald(const __hip_bfloat16* __restrict__ hdst, int N,
                      const float* __restrict__ W,     // [64,64]
                      const float* __restrict__ avec,  // [4,16]
                      float* __restrict__ ald)         // [N,4]
{
    __shared__ float Weff[64 * 4];
    __shared__ float hsh[64 * 65];
    int tid = threadIdx.x;
    {
        int k = tid >> 2, hh = tid & 3;
        float s = 0.f;
        for (int c = 0; c < 16; ++c)
            s += W[k * 64 + hh * 16 + c] * avec[hh * 16 + c];
        Weff[k * 4 + hh] = s;
    }
    size_t base = (size_t)blockIdx.x * 64 * 64;
    size_t lim = (size_t)N * 64;
    for (int i = tid; i < 4096; i += 256) {
        size_t g = base + i;
        hsh[(i >> 6) * 65 + (i & 63)] = (g < lim) ? b2f(hdst[g]) : 0.f;
    }
    __syncthreads();
    int nl = tid & 63, hh = tid >> 6;
    int n = blockIdx.x * 64 + nl;
    if (n >= N) return;
    float acc = 0.f;
#pragma unroll
    for (int k = 0; k < 64; ++k) acc += hsh[nl * 65 + k] * Weff[k * 4 + hh];
    ald[(size_t)n * 4 + hh] = acc;
}

// ---------------- edge pass: numer/denom accumulation -----------------------
__global__ void k_edge(const int* __restrict__ ei, int E,
                       const __hip_bfloat16* __restrict__ hs,
                       const float* __restrict__ als,
                       const float* __restrict__ ald,
                       float* __restrict__ numer,
                       float* __restrict__ denom)
{
    int tid = threadIdx.x;
    int e = blockIdx.x * 4 + (tid >> 6);
    if (e >= E) return;
    int c = tid & 63, hh = c >> 4;
    int s = ei[e], d = ei[E + e];
    float x = als[s * 4 + hh] + ald[d * 4 + hh];
    x = (x > 0.f) ? x : 0.2f * x;           // leaky_relu 0.2
    float w = __expf(fminf(x, 60.f));
    float val = w * b2f(hs[(size_t)s * 64 + c]);
#if defined(__gfx90a__) || defined(__gfx940__) || defined(__gfx941__) || defined(__gfx942__) || defined(__gfx950__)
    unsafeAtomicAdd(&numer[(size_t)d * 64 + c], val);
    if ((c & 15) == 0) unsafeAtomicAdd(&denom[(size_t)d * 4 + hh], w);
#else
    atomicAdd(&numer[(size_t)d * 64 + c], val);
    if ((c & 15) == 0) atomicAdd(&denom[(size_t)d * 4 + hh], w);
#endif
}

// --------- finalize: h = relu(LN(h + num0/den0 + b0 [+ num1/den1 + b1])) ---
__global__ void k_finalize(__hip_bfloat16* __restrict__ h, int N,
                           const float* __restrict__ num0, const float* __restrict__ den0,
                           const float* __restrict__ b0,
                           const float* __restrict__ num1, const float* __restrict__ den1,
                           const float* __restrict__ b1,
                           const float* __restrict__ g, const float* __restrict__ bb,
                           void* __restrict__ outv, size_t obase,
                           const int* __restrict__ flag)
{
    int tid = threadIdx.x;
    int c = tid & 63, hh = c >> 4;
    int n = blockIdx.x * 4 + (tid >> 6);
    if (n >= N) return;
    size_t i = (size_t)n * 64 + c;
    float acc = b2f(h[i]) + num0[i] / (den0[(size_t)n * 4 + hh] + 1e-16f) + b0[c];
    if (num1) acc += num1[i] / (den1[(size_t)n * 4 + hh] + 1e-16f) + b1[c];
    float s = acc;
#pragma unroll
    for (int off = 32; off >= 1; off >>= 1) s += __shfl_xor(s, off, 64);
    float mu = s * (1.f / 64.f);
    float dlt = acc - mu;
    float v = dlt * dlt;
#pragma unroll
    for (int off = 32; off >= 1; off >>= 1) v += __shfl_xor(v, off, 64);
    float y = dlt * rsqrtf(v * (1.f / 64.f) + 1e-5f) * g[c] + bb[c];
    y = fmaxf(y, 0.f);
    h[i] = f2b(y);
    if (outv) {
        if (*flag) ((float*)outv)[obase + i] = y;
        else       ((__hip_bfloat16*)outv)[obase + i] = f2b(y);
    }
}

extern "C" void kernel_launch(void* const* d_in, const int* in_sizes, int n_in,
                              void* d_out, int out_size, void* d_ws, size_t ws_size,
                              hipStream_t stream)
{
    (void)n_in; (void)out_size; (void)ws_size;
    char* ws = (char*)d_ws;
    int* flag = (int*)ws;
    float* params = (float*)(ws + 256);

    size_t off[17]; off[0] = 0;
    for (int i = 0; i < 16; ++i) off[i + 1] = off[i] + (size_t)in_sizes[i];

    const float* x_i = params + off[0];
    const float* x_q = params + off[1];
    const float* x_t = params + off[2];
    const float* Wi = params + off[3]; const float* bi = params + off[4];
    const float* Wq = params + off[5]; const float* bq = params + off[6];
    const float* Wt = params + off[7]; const float* bt = params + off[8];
    const float* Wsrc = params + off[9];
    const float* Wdst = params + off[10];
    const float* asrc = params + off[11];
    const float* adst = params + off[12];
    const float* cbias = params + off[13];
    const float* lng = params + off[14];
    const float* lnb = params + off[15];

    const int* ei[5];
    for (int j = 0; j < 5; ++j) ei[j] = (const int*)d_in[16 + j];

    __hip_bfloat16* h   = (__hip_bfloat16*)(ws + 7600000);
    __hip_bfloat16* h_i = h;
    __hip_bfloat16* h_q = h + (size_t)NI * 64;
    __hip_bfloat16* h_t = h + (size_t)(NI + NQ) * 64;
    __hip_bfloat16* hsbuf = (__hip_bfloat16*)(ws + 39600000);
    float* als = (float*)(ws + 52400000);
    float* ald = (float*)(ws + 54000000);
    float* num[3] = { (float*)(ws + 55600000), (float*)(ws + 81200000), (float*)(ws + 106800000) };
    float* den[3] = { (float*)(ws + 132400000), (float*)(ws + 134000000), (float*)(ws + 135600000) };

    // ---- dtype detect + widen all float params to f32 ----
    k_detect<<<1, 256, 0, stream>>>((const unsigned short*)d_in[0], flag);
    ConvArgs ca;
    for (int i = 0; i < 16; ++i) {
        ca.src[i] = d_in[i];
        ca.dst[i] = params + off[i];
        ca.n[i] = in_sizes[i];
    }
    k_convert<<<dim3(3125, 16), 256, 0, stream>>>(ca, flag);

    k_inproj<<<(NI + 3) / 4, 256, 0, stream>>>(x_i, NI, 8, Wi, bi, h_i);
    k_inproj<<<(NQ + 3) / 4, 256, 0, stream>>>(x_q, NQ, 6, Wq, bq, h_q);
    k_inproj<<<(NT + 3) / 4, 256, 0, stream>>>(x_t, NT, 8, Wt, bt, h_t);

    const int Nsrc_of[5] = { NI, NI, NQ, NQ, NT };
    const int Ndst_of[5] = { NI, NQ, NI, NT, NQ };
    __hip_bfloat16* hsrc_of[5] = { h_i, h_i, h_q, h_q, h_t };
    __hip_bfloat16* hdst_of[5] = { h_i, h_q, h_i, h_t, h_q };

    for (int l = 0; l < 2; ++l) {
        auto run = [&](int j, int sl) {
            int Ns = Nsrc_of[j], Nd = Ndst_of[j];
            const float* Wsj = Wsrc + (size_t)(l * 5 + j) * 4096;
            const float* Wdj = Wdst + (size_t)(l * 5 + j) * 4096;
            const float* asj = asrc + (l * 5 + j) * 64;
            const float* adj = adst + (l * 5 + j) * 64;
            k_transform<<<(Ns + 3) / 4, 256, 0, stream>>>(hsrc_of[j], Ns, Wsj, asj, hsbuf, als);
            k_ald<<<(Nd + 63) / 64, 256, 0, stream>>>(hdst_of[j], Nd, Wdj, adj, ald);
            hipMemsetAsync(num[sl], 0, (size_t)Nd * 64 * 4, stream);
            hipMemsetAsync(den[sl], 0, (size_t)Nd * 4 * 4, stream);
            k_edge<<<(NE + 3) / 4, 256, 0, stream>>>(ei[j], NE, hsbuf, als, ald, num[sl], den[sl]);
        };
        bool last = (l == 1);
        void* ov = last ? d_out : nullptr;

        run(0, 0);  // idle->idle   -> slot0
        run(1, 2);  // idle->quasi  -> slot2
        run(2, 1);  // quasi->idle  -> slot1
        k_finalize<<<(NI + 3) / 4, 256, 0, stream>>>(h_i, NI,
            num[0], den[0], cbias + (size_t)(l * 5 + 0) * 64,
            num[1], den[1], cbias + (size_t)(l * 5 + 2) * 64,
            lng + (size_t)(l * 3 + 0) * 64, lnb + (size_t)(l * 3 + 0) * 64,
            ov, 0, flag);
        run(3, 0);  // quasi->task  -> slot0 (idle slots free after finalize)
        run(4, 1);  // task->quasi  -> slot1
        k_finalize<<<(NQ + 3) / 4, 256, 0, stream>>>(h_q, NQ,
            num[2], den[2], cbias + (size_t)(l * 5 + 1) * 64,
            num[1], den[1], cbias + (size_t)(l * 5 + 4) * 64,
            lng + (size_t)(l * 3 + 1) * 64, lnb + (size_t)(l * 3 + 1) * 64,
            ov, (size_t)NI * 64, flag);
        k_finalize<<<(NT + 3) / 4, 256, 0, stream>>>(h_t, NT,
            num[0], den[0], cbias + (size_t)(l * 5 + 3) * 64,
            nullptr, nullptr, nullptr,
            lng + (size_t)(l * 3 + 2) * 64, lnb + (size_t)(l * 3 + 2) * 64,
            ov, (size_t)(NI + NQ) * 64, flag);
    }
}

// Round 4
// 1370.894 us; speedup vs baseline: 1.5932x; 1.5932x over previous
//
#include <hip/hip_runtime.h>
#include <hip/hip_bf16.h>
#include <cstddef>

// MCSHeteroGNN: 2-layer hetero GAT, CSR-gather formulation (no f32 scatter atomics).
// Node types: idle(100k), quasi(100k), task(50k). 5 edge types x 500k edges.
// Float dtype (f32 vs bf16) detected at runtime; params widened to f32 in ws.
//
// etypes: 0 ii(idle->idle) 1 iq(idle->quasi) 2 qi(quasi->idle)
//         3 qt(quasi->task) 4 tq(task->quasi)
// hs/als row bases per etype: 0,100k,200k,300k,400k (total 450k rows)
//
// ws layout (bytes), total ~118.5 MB:
//   flag    @ 0
//   params  @ 256         (7,544,832: all 16 float inputs as f32)
//   h  bf16 @ 7,600,000   (32,000,000) [idle|quasi|task]
//   hs bf16 @ 39,600,000  (57,600,000) [450k x 64]
//   als f32 @ 97,200,000  ( 7,200,000) [450k x 4]
//   rowptr  @104,400,000  (5 x 400,032)
//   cursor  @106,400,320  (5 x 400,032)
//   cols    @108,400,480  (5 x 2,000,000)
//   part    @118,400,480  (2,048)

static constexpr int NI = 100000, NQ = 100000, NT = 50000, NE = 500000;

__device__ __forceinline__ float b2f(__hip_bfloat16 x) { return __bfloat162float(x); }
__device__ __forceinline__ __hip_bfloat16 f2b(float x) { return __float2bfloat16(x); }

// ---- dtype sniff: even halfwords of an f32 randn buffer have random
// "exponent" bits; bf16 randn halfwords have sane exponents.
__global__ void k_detect(const unsigned short* __restrict__ x, int* __restrict__ flag)
{
    __shared__ int sh[256];
    int tid = threadIdx.x;
    int sane = 0;
    for (int i = tid * 2; i < 2048; i += 512) {
        unsigned short h = x[i];
        int e = (h >> 7) & 0xFF;
        if (h == 0 || (e >= 100 && e <= 140)) sane++;
    }
    sh[tid] = sane;
    __syncthreads();
    for (int s = 128; s; s >>= 1) { if (tid < s) sh[tid] += sh[tid + s]; __syncthreads(); }
    if (tid == 0) *flag = (sh[0] < 512) ? 1 : 0;   // 1 = buffers are f32
}

struct ConvArgs { const void* src[16]; float* dst[16]; int n[16]; };

__global__ void k_convert(ConvArgs a, const int* __restrict__ flag)
{
    int t = blockIdx.y;
    int i = blockIdx.x * 256 + threadIdx.x;
    if (i >= a.n[t]) return;
    float v = (*flag) ? ((const float*)a.src[t])[i]
                      : b2f(((const __hip_bfloat16*)a.src[t])[i]);
    a.dst[t][i] = v;
}

// ---------------- input projection: h = relu(x @ W + b) --------------------
__global__ void k_inproj(const float* __restrict__ x, int N, int F,
                         const float* __restrict__ W, const float* __restrict__ b,
                         __hip_bfloat16* __restrict__ h)
{
    __shared__ float Wsh[8 * 64];
    __shared__ float bsh[64];
    int tid = threadIdx.x;
    for (int i = tid; i < F * 64; i += 256) Wsh[i] = W[i];
    if (tid < 64) bsh[tid] = b[tid];
    __syncthreads();
    int col = tid & 63;
    int n = blockIdx.x * 4 + (tid >> 6);
    if (n >= N) return;
    const float* xr = x + (size_t)n * F;
    float acc = bsh[col];
    for (int k = 0; k < F; ++k) acc += xr[k] * Wsh[k * 64 + col];
    h[(size_t)n * 64 + col] = f2b(fmaxf(acc, 0.f));
}

// ------- all 5 etypes' hs = h_src @ Wsrc (bf16) + als, one dispatch --------
struct TfArgs {
    const __hip_bfloat16* hsrc[5];
    const float* W[5];
    const float* avec[5];
    __hip_bfloat16* hs[5];
    float* als[5];
};
__global__ void k_transform_all(TfArgs a)
{
    __shared__ float Wsh[4096];
    __shared__ float ash[64];
    __shared__ float hsh[4][64];
    int tid = threadIdx.x;
    int base = blockIdx.x * 16;               // 16 rows per block; etype boundaries are x16
    int j = base / 100000;
    const float* W = a.W[j];
    for (int i = tid; i < 4096; i += 256) Wsh[i] = W[i];
    if (tid < 64) ash[tid] = a.avec[j][tid];
    __syncthreads();
    int wid = tid >> 6, c = tid & 63;
    int nl0 = base - j * 100000;
    const __hip_bfloat16* hsrc = a.hsrc[j];
    __hip_bfloat16* hs = a.hs[j];
    float* als = a.als[j];
    for (int r = 0; r < 4; ++r) {
        int nl = nl0 + r * 4 + wid;
        hsh[wid][c] = b2f(hsrc[(size_t)nl * 64 + c]);   // wave-private row, no barrier
        float acc = 0.f;
#pragma unroll
        for (int k = 0; k < 64; ++k) acc += hsh[wid][k] * Wsh[k * 64 + c];
        hs[(size_t)nl * 64 + c] = f2b(acc);
        float p = acc * ash[c];
        p += __shfl_xor(p, 8, 16);
        p += __shfl_xor(p, 4, 16);
        p += __shfl_xor(p, 2, 16);
        p += __shfl_xor(p, 1, 16);
        if ((c & 15) == 0) als[(size_t)nl * 4 + (c >> 4)] = p;
    }
}

// ------------------------- counting sort by dst ----------------------------
__global__ void k_hist(const int* __restrict__ ei, int E, int* __restrict__ rowptr)
{
    int e = blockIdx.x * 256 + threadIdx.x;
    if (e >= E) return;
    atomicAdd(&rowptr[ei[E + e] + 1], 1);
}
__global__ void k_scan_block(int* __restrict__ a, int n, int* __restrict__ part)
{
    __shared__ int sh[256];
    int tid = threadIdx.x;
    int i = blockIdx.x * 256 + tid;
    int v = (i < n) ? a[i] : 0;
    sh[tid] = v; __syncthreads();
    for (int off = 1; off < 256; off <<= 1) {
        int t = (tid >= off) ? sh[tid - off] : 0;
        __syncthreads();
        sh[tid] += t;
        __syncthreads();
    }
    if (i < n) a[i] = sh[tid];
    if (tid == 255) part[blockIdx.x] = sh[255];
}
__global__ void k_scan_part(int* __restrict__ part, int nb)
{
    __shared__ int sh[512];
    int tid = threadIdx.x;
    int v = (tid < nb) ? part[tid] : 0;
    sh[tid] = v; __syncthreads();
    for (int off = 1; off < 512; off <<= 1) {
        int t = (tid >= off) ? sh[tid - off] : 0;
        __syncthreads();
        sh[tid] += t;
        __syncthreads();
    }
    if (tid < nb) part[tid] = sh[tid] - v;    // exclusive
}
__global__ void k_scan_add(int* __restrict__ a, int n, const int* __restrict__ part)
{
    int i = blockIdx.x * 256 + threadIdx.x;
    if (i < n) a[i] += part[blockIdx.x];
}
__global__ void k_scatter(const int* __restrict__ ei, int E,
                          int* __restrict__ cursor, int* __restrict__ cols)
{
    int e = blockIdx.x * 256 + threadIdx.x;
    if (e >= E) return;
    int s = ei[e], d = ei[E + e];
    int pos = atomicAdd(&cursor[d], 1);
    cols[pos] = s;
}

// ------------------ fused per-dst GAT gather + LN + ReLU -------------------
__device__ __forceinline__ float gat_side(int n, int c, int hh, float hrow,
    const float* We, const int* __restrict__ rp, const int* __restrict__ cols,
    const __hip_bfloat16* __restrict__ hs, const float* __restrict__ als)
{
    float aldv = 0.f;
#pragma unroll
    for (int hp = 0; hp < 4; ++hp) {
        float v = hrow * We[c * 4 + hp];
        v += __shfl_xor(v, 32, 64);
        v += __shfl_xor(v, 16, 64);
        v += __shfl_xor(v, 8, 64);
        v += __shfl_xor(v, 4, 64);
        v += __shfl_xor(v, 2, 64);
        v += __shfl_xor(v, 1, 64);
        if (hh == hp) aldv = v;
    }
    float acc = 0.f, den = 0.f;
    int beg = rp[n], end = rp[n + 1];
    for (int e = beg; e < end; ++e) {
        int s = cols[e];
        float al = als[(size_t)s * 4 + hh] + aldv;
        al = (al > 0.f) ? al : 0.2f * al;          // leaky_relu 0.2
        float w = __expf(fminf(al, 60.f));
        acc += w * b2f(hs[(size_t)s * 64 + c]);
        den += w;
    }
    return acc / (den + 1e-16f);
}

struct DstArgs {
    __hip_bfloat16* h; int N; int net; int last;
    const int* rp0; const int* cols0; const __hip_bfloat16* hs0; const float* als0;
    const float* Wd0; const float* ad0; const float* b0;
    const int* rp1; const int* cols1; const __hip_bfloat16* hs1; const float* als1;
    const float* Wd1; const float* ad1; const float* b1;
    const float* g; const float* bb;
    void* out; size_t obase; const int* flag;
};
__global__ void k_dst(DstArgs a)
{
    __shared__ float We0[256], We1[256];
    int tid = threadIdx.x;
    {
        int k = tid >> 2, h2 = tid & 3;
        float s0 = 0.f;
        for (int cc = 0; cc < 16; ++cc)
            s0 += a.Wd0[k * 64 + h2 * 16 + cc] * a.ad0[h2 * 16 + cc];
        We0[tid] = s0;
        if (a.net > 1) {
            float s1 = 0.f;
            for (int cc = 0; cc < 16; ++cc)
                s1 += a.Wd1[k * 64 + h2 * 16 + cc] * a.ad1[h2 * 16 + cc];
            We1[tid] = s1;
        }
    }
    __syncthreads();
    int wid = tid >> 6, c = tid & 63, hh = c >> 4;
    float b0c = a.b0[c];
    float b1c = (a.net > 1) ? a.b1[c] : 0.f;
    float gc = a.g[c], bbc = a.bb[c];
    int base = blockIdx.x * 16;               // 16 nodes/block; N is a multiple of 16
    for (int r = 0; r < 4; ++r) {
        int n = base + r * 4 + wid;
        if (n >= a.N) continue;
        size_t i64 = (size_t)n * 64 + c;
        float hrow = b2f(a.h[i64]);
        float x = hrow + b0c + b1c;
        x += gat_side(n, c, hh, hrow, We0, a.rp0, a.cols0, a.hs0, a.als0);
        if (a.net > 1)
            x += gat_side(n, c, hh, hrow, We1, a.rp1, a.cols1, a.hs1, a.als1);
        float s = x;
#pragma unroll
        for (int off = 32; off >= 1; off >>= 1) s += __shfl_xor(s, off, 64);
        float mu = s * (1.f / 64.f);
        float dlt = x - mu;
        float v2 = dlt * dlt;
#pragma unroll
        for (int off = 32; off >= 1; off >>= 1) v2 += __shfl_xor(v2, off, 64);
        float y = dlt * rsqrtf(v2 * (1.f / 64.f) + 1e-5f) * gc + bbc;
        y = fmaxf(y, 0.f);
        if (!a.last) a.h[i64] = f2b(y);
        else {
            if (*a.flag) ((float*)a.out)[a.obase + i64] = y;
            else         ((__hip_bfloat16*)a.out)[a.obase + i64] = f2b(y);
        }
    }
}

extern "C" void kernel_launch(void* const* d_in, const int* in_sizes, int n_in,
                              void* d_out, int out_size, void* d_ws, size_t ws_size,
                              hipStream_t stream)
{
    (void)n_in; (void)out_size; (void)ws_size;
    char* ws = (char*)d_ws;
    int* flag = (int*)ws;
    float* params = (float*)(ws + 256);

    size_t off[17]; off[0] = 0;
    for (int i = 0; i < 16; ++i) off[i + 1] = off[i] + (size_t)in_sizes[i];

    const float* x_i = params + off[0];
    const float* x_q = params + off[1];
    const float* x_t = params + off[2];
    const float* Wi = params + off[3]; const float* bi = params + off[4];
    const float* Wq = params + off[5]; const float* bq = params + off[6];
    const float* Wt = params + off[7]; const float* bt = params + off[8];
    const float* Wsrc = params + off[9];
    const float* Wdst = params + off[10];
    const float* asrc = params + off[11];
    const float* adst = params + off[12];
    const float* cbias = params + off[13];
    const float* lng = params + off[14];
    const float* lnb = params + off[15];

    const int* ei[5];
    for (int j = 0; j < 5; ++j) ei[j] = (const int*)d_in[16 + j];

    __hip_bfloat16* h   = (__hip_bfloat16*)(ws + 7600000);
    __hip_bfloat16* h_i = h;
    __hip_bfloat16* h_q = h + (size_t)NI * 64;
    __hip_bfloat16* h_t = h + (size_t)(NI + NQ) * 64;
    __hip_bfloat16* hs_all = (__hip_bfloat16*)(ws + 39600000);
    float* als_all = (float*)(ws + 97200000);
    const size_t rowbase[5] = { 0, 100000, 200000, 300000, 400000 };

    const size_t RPS = 400032;
    int* rowptr[5]; int* cursor[5]; int* cols[5];
    for (int j = 0; j < 5; ++j) {
        rowptr[j] = (int*)(ws + 104400000 + j * RPS);
        cursor[j] = (int*)(ws + 106400320 + j * RPS);
        cols[j]   = (int*)(ws + 108400480 + (size_t)j * 2000000);
    }
    int* part = (int*)(ws + 118400480);

    // ---- dtype detect + widen all float params to f32 ----
    k_detect<<<1, 256, 0, stream>>>((const unsigned short*)d_in[0], flag);
    ConvArgs ca;
    for (int i = 0; i < 16; ++i) { ca.src[i] = d_in[i]; ca.dst[i] = params + off[i]; ca.n[i] = in_sizes[i]; }
    k_convert<<<dim3(3125, 16), 256, 0, stream>>>(ca, flag);

    // ---- input projections ----
    k_inproj<<<(NI + 3) / 4, 256, 0, stream>>>(x_i, NI, 8, Wi, bi, h_i);
    k_inproj<<<(NQ + 3) / 4, 256, 0, stream>>>(x_q, NQ, 6, Wq, bq, h_q);
    k_inproj<<<(NT + 3) / 4, 256, 0, stream>>>(x_t, NT, 8, Wt, bt, h_t);

    // ---- counting sort of each edge list by dst (reused by both layers) ----
    const int Ndst_of[5] = { NI, NQ, NI, NT, NQ };
    for (int j = 0; j < 5; ++j) {
        int n = Ndst_of[j] + 1;
        int nb = (n + 255) / 256;
        hipMemsetAsync(rowptr[j], 0, (size_t)n * 4, stream);
        k_hist<<<(NE + 255) / 256, 256, 0, stream>>>(ei[j], NE, rowptr[j]);
        k_scan_block<<<nb, 256, 0, stream>>>(rowptr[j], n, part);
        k_scan_part<<<1, 512, 0, stream>>>(part, nb);
        k_scan_add<<<nb, 256, 0, stream>>>(rowptr[j], n, part);
        hipMemcpyAsync(cursor[j], rowptr[j], (size_t)n * 4, hipMemcpyDeviceToDevice, stream);
        k_scatter<<<(NE + 255) / 256, 256, 0, stream>>>(ei[j], NE, cursor[j], cols[j]);
    }

    const __hip_bfloat16* hsrc_of[5] = { h_i, h_i, h_q, h_q, h_t };

    for (int l = 0; l < 2; ++l) {
        // all 5 transforms read pre-update h -> run before any dst kernel
        TfArgs ta;
        for (int j = 0; j < 5; ++j) {
            ta.hsrc[j] = hsrc_of[j];
            ta.W[j] = Wsrc + (size_t)(l * 5 + j) * 4096;
            ta.avec[j] = asrc + (l * 5 + j) * 64;
            ta.hs[j] = hs_all + rowbase[j] * 64;
            ta.als[j] = als_all + rowbase[j] * 4;
        }
        k_transform_all<<<450000 / 16, 256, 0, stream>>>(ta);

        int last = (l == 1);
        auto dst_args = [&](__hip_bfloat16* hd, int N, int j0, int j1, int lnidx,
                            size_t obase) {
            DstArgs da;
            da.h = hd; da.N = N; da.net = (j1 >= 0) ? 2 : 1; da.last = last;
            da.rp0 = rowptr[j0]; da.cols0 = cols[j0];
            da.hs0 = hs_all + rowbase[j0] * 64; da.als0 = als_all + rowbase[j0] * 4;
            da.Wd0 = Wdst + (size_t)(l * 5 + j0) * 4096;
            da.ad0 = adst + (l * 5 + j0) * 64;
            da.b0 = cbias + (size_t)(l * 5 + j0) * 64;
            int jj = (j1 >= 0) ? j1 : j0;
            da.rp1 = rowptr[jj]; da.cols1 = cols[jj];
            da.hs1 = hs_all + rowbase[jj] * 64; da.als1 = als_all + rowbase[jj] * 4;
            da.Wd1 = Wdst + (size_t)(l * 5 + jj) * 4096;
            da.ad1 = adst + (l * 5 + jj) * 64;
            da.b1 = cbias + (size_t)(l * 5 + jj) * 64;
            da.g = lng + (size_t)(l * 3 + lnidx) * 64;
            da.bb = lnb + (size_t)(l * 3 + lnidx) * 64;
            da.out = d_out; da.obase = obase; da.flag = flag;
            return da;
        };
        k_dst<<<NI / 16, 256, 0, stream>>>(dst_args(h_i, NI, 0, 2, 0, 0));
        k_dst<<<NQ / 16, 256, 0, stream>>>(dst_args(h_q, NQ, 1, 4, 1, (size_t)NI * 64));
        k_dst<<<NT / 16, 256, 0, stream>>>(dst_args(h_t, NT, 3, -1, 2, (size_t)(NI + NQ) * 64));
    }
}

// Round 5
// 1116.549 us; speedup vs baseline: 1.9561x; 1.2278x over previous
//
#include <hip/hip_runtime.h>
#include <hip/hip_bf16.h>
#include <cstddef>

// MCSHeteroGNN: 2-layer hetero GAT, CSR-gather formulation (no f32 scatter atomics).
// Node types: idle(100k), quasi(100k), task(50k). 5 edge types x 500k edges.
// Float dtype (f32 vs bf16) detected at runtime; small params widened to f32 in ws;
// features read directly with dtype flag. Edge loop unrolled x4 for MLP.
//
// ws layout (bytes), total ~118.5 MB:
//   flag    @ 0
//   params  @ 256         (f32 widened params; feature slots unused)
//   h  bf16 @ 7,600,000   (32,000,000) [idle|quasi|task]
//   hs bf16 @ 39,600,000  (57,600,000) [450k x 64]
//   als f32 @ 97,200,000  ( 7,200,000) [450k x 4]
//   rowptr  @104,400,000  (5 x 400,032)
//   cursor  @106,400,320  (5 x 400,032)
//   cols    @108,400,480  (5 x 2,000,000)
//   part    @118,400,480  (2,048)

static constexpr int NI = 100000, NQ = 100000, NT = 50000, NE = 500000;

__device__ __forceinline__ float b2f(__hip_bfloat16 x) { return __bfloat162float(x); }
__device__ __forceinline__ __hip_bfloat16 f2b(float x) { return __float2bfloat16(x); }

__global__ void k_detect(const unsigned short* __restrict__ x, int* __restrict__ flag)
{
    __shared__ int sh[256];
    int tid = threadIdx.x;
    int sane = 0;
    for (int i = tid * 2; i < 2048; i += 512) {
        unsigned short h = x[i];
        int e = (h >> 7) & 0xFF;
        if (h == 0 || (e >= 100 && e <= 140)) sane++;
    }
    sh[tid] = sane;
    __syncthreads();
    for (int s = 128; s; s >>= 1) { if (tid < s) sh[tid] += sh[tid + s]; __syncthreads(); }
    if (tid == 0) *flag = (sh[0] < 512) ? 1 : 0;   // 1 = buffers are f32
}

struct ConvArgs { const void* src[16]; float* dst[16]; int n[16]; };

__global__ void k_convert(ConvArgs a, const int* __restrict__ flag)
{
    int t = blockIdx.y;
    int i = blockIdx.x * 256 + threadIdx.x;
    if (i >= a.n[t]) return;
    float v = (*flag) ? ((const float*)a.src[t])[i]
                      : b2f(((const __hip_bfloat16*)a.src[t])[i]);
    a.dst[t][i] = v;
}

// ------------- input projection: h = relu(x @ W + b), dual-dtype -----------
__global__ void k_inproj(const void* __restrict__ xv, int N, int F,
                         const float* __restrict__ W, const float* __restrict__ b,
                         __hip_bfloat16* __restrict__ h, const int* __restrict__ flag)
{
    __shared__ float Wsh[8 * 64];
    __shared__ float bsh[64];
    int tid = threadIdx.x;
    for (int i = tid; i < F * 64; i += 256) Wsh[i] = W[i];
    if (tid < 64) bsh[tid] = b[tid];
    __syncthreads();
    int col = tid & 63;
    int n = blockIdx.x * 4 + (tid >> 6);
    if (n >= N) return;
    float acc = bsh[col];
    if (*flag) {
        const float* xr = (const float*)xv + (size_t)n * F;
        for (int k = 0; k < F; ++k) acc += xr[k] * Wsh[k * 64 + col];
    } else {
        const __hip_bfloat16* xr = (const __hip_bfloat16*)xv + (size_t)n * F;
        for (int k = 0; k < F; ++k) acc += b2f(xr[k]) * Wsh[k * 64 + col];
    }
    h[(size_t)n * 64 + col] = f2b(fmaxf(acc, 0.f));
}

// ------- all 5 etypes' hs = h_src @ Wsrc (bf16) + als, one dispatch --------
struct TfArgs {
    const __hip_bfloat16* hsrc[5];
    const float* W[5];
    const float* avec[5];
    __hip_bfloat16* hs[5];
    float* als[5];
};
__global__ void k_transform_all(TfArgs a)
{
    __shared__ float Wsh[4096];
    __shared__ float ash[64];
    __shared__ float hsh[4][64];
    int tid = threadIdx.x;
    int base = blockIdx.x * 16;
    int j = base / 100000;
    const float* W = a.W[j];
    for (int i = tid; i < 4096; i += 256) Wsh[i] = W[i];
    if (tid < 64) ash[tid] = a.avec[j][tid];
    __syncthreads();
    int wid = tid >> 6, c = tid & 63;
    int nl0 = base - j * 100000;
    const __hip_bfloat16* hsrc = a.hsrc[j];
    __hip_bfloat16* hs = a.hs[j];
    float* als = a.als[j];
    for (int r = 0; r < 4; ++r) {
        int nl = nl0 + r * 4 + wid;
        hsh[wid][c] = b2f(hsrc[(size_t)nl * 64 + c]);
        float acc = 0.f;
#pragma unroll
        for (int k = 0; k < 64; ++k) acc += hsh[wid][k] * Wsh[k * 64 + c];
        hs[(size_t)nl * 64 + c] = f2b(acc);
        float p = acc * ash[c];
        p += __shfl_xor(p, 8, 16);
        p += __shfl_xor(p, 4, 16);
        p += __shfl_xor(p, 2, 16);
        p += __shfl_xor(p, 1, 16);
        if ((c & 15) == 0) als[(size_t)nl * 4 + (c >> 4)] = p;
    }
}

// ------------------------- counting sort by dst ----------------------------
__global__ void k_hist(const int* __restrict__ ei, int E, int* __restrict__ rowptr)
{
    int e = blockIdx.x * 256 + threadIdx.x;
    if (e >= E) return;
    atomicAdd(&rowptr[ei[E + e] + 1], 1);
}
__global__ void k_scan_block(int* __restrict__ a, int n, int* __restrict__ part)
{
    __shared__ int sh[256];
    int tid = threadIdx.x;
    int i = blockIdx.x * 256 + tid;
    int v = (i < n) ? a[i] : 0;
    sh[tid] = v; __syncthreads();
    for (int off = 1; off < 256; off <<= 1) {
        int t = (tid >= off) ? sh[tid - off] : 0;
        __syncthreads();
        sh[tid] += t;
        __syncthreads();
    }
    if (i < n) a[i] = sh[tid];
    if (tid == 255) part[blockIdx.x] = sh[255];
}
__global__ void k_scan_part(int* __restrict__ part, int nb)
{
    __shared__ int sh[512];
    int tid = threadIdx.x;
    int v = (tid < nb) ? part[tid] : 0;
    sh[tid] = v; __syncthreads();
    for (int off = 1; off < 512; off <<= 1) {
        int t = (tid >= off) ? sh[tid - off] : 0;
        __syncthreads();
        sh[tid] += t;
        __syncthreads();
    }
    if (tid < nb) part[tid] = sh[tid] - v;    // exclusive
}
__global__ void k_scan_add(int* __restrict__ a, int n, const int* __restrict__ part)
{
    int i = blockIdx.x * 256 + threadIdx.x;
    if (i < n) a[i] += part[blockIdx.x];
}
__global__ void k_scatter(const int* __restrict__ ei, int E,
                          int* __restrict__ cursor, int* __restrict__ cols)
{
    int e = blockIdx.x * 256 + threadIdx.x;
    if (e >= E) return;
    int s = ei[e], d = ei[E + e];
    int pos = atomicAdd(&cursor[d], 1);
    cols[pos] = s;
}

// ------------------ fused per-dst GAT gather + LN + ReLU -------------------
__device__ __forceinline__ float gat_side(int n, int c, int hh, float hrow,
    const float* We, const int* __restrict__ rp, const int* __restrict__ cols,
    const __hip_bfloat16* __restrict__ hs, const float* __restrict__ als)
{
    float aldv = 0.f;
#pragma unroll
    for (int hp = 0; hp < 4; ++hp) {
        float v = hrow * We[c * 4 + hp];
        v += __shfl_xor(v, 32, 64);
        v += __shfl_xor(v, 16, 64);
        v += __shfl_xor(v, 8, 64);
        v += __shfl_xor(v, 4, 64);
        v += __shfl_xor(v, 2, 64);
        v += __shfl_xor(v, 1, 64);
        if (hh == hp) aldv = v;
    }
    float acc = 0.f, den = 0.f;
    int e = rp[n], end = rp[n + 1];
    // 4-wide unroll: 4 independent col loads, then 4 independent gathers in
    // flight together -> 4x memory-level parallelism vs serial chain.
    for (; e + 4 <= end; e += 4) {
        int s0 = cols[e], s1 = cols[e + 1], s2 = cols[e + 2], s3 = cols[e + 3];
        float a0 = als[(size_t)s0 * 4 + hh];
        float a1 = als[(size_t)s1 * 4 + hh];
        float a2 = als[(size_t)s2 * 4 + hh];
        float a3 = als[(size_t)s3 * 4 + hh];
        float g0 = b2f(hs[(size_t)s0 * 64 + c]);
        float g1 = b2f(hs[(size_t)s1 * 64 + c]);
        float g2 = b2f(hs[(size_t)s2 * 64 + c]);
        float g3 = b2f(hs[(size_t)s3 * 64 + c]);
        a0 += aldv; a1 += aldv; a2 += aldv; a3 += aldv;
        a0 = (a0 > 0.f) ? a0 : 0.2f * a0;
        a1 = (a1 > 0.f) ? a1 : 0.2f * a1;
        a2 = (a2 > 0.f) ? a2 : 0.2f * a2;
        a3 = (a3 > 0.f) ? a3 : 0.2f * a3;
        float w0 = __expf(fminf(a0, 60.f));
        float w1 = __expf(fminf(a1, 60.f));
        float w2 = __expf(fminf(a2, 60.f));
        float w3 = __expf(fminf(a3, 60.f));
        acc += w0 * g0; den += w0;
        acc += w1 * g1; den += w1;
        acc += w2 * g2; den += w2;
        acc += w3 * g3; den += w3;
    }
    for (; e < end; ++e) {
        int s = cols[e];
        float al = als[(size_t)s * 4 + hh];
        float gg = b2f(hs[(size_t)s * 64 + c]);
        al += aldv;
        al = (al > 0.f) ? al : 0.2f * al;
        float w = __expf(fminf(al, 60.f));
        acc += w * gg;
        den += w;
    }
    return acc / (den + 1e-16f);
}

struct DstArgs {
    __hip_bfloat16* h; int N; int net; int last;
    const int* rp0; const int* cols0; const __hip_bfloat16* hs0; const float* als0;
    const float* Wd0; const float* ad0; const float* b0;
    const int* rp1; const int* cols1; const __hip_bfloat16* hs1; const float* als1;
    const float* Wd1; const float* ad1; const float* b1;
    const float* g; const float* bb;
    void* out; size_t obase; const int* flag;
};
__global__ void k_dst(DstArgs a)
{
    __shared__ float We0[256], We1[256];
    int tid = threadIdx.x;
    {
        int k = tid >> 2, h2 = tid & 3;
        float s0 = 0.f;
        for (int cc = 0; cc < 16; ++cc)
            s0 += a.Wd0[k * 64 + h2 * 16 + cc] * a.ad0[h2 * 16 + cc];
        We0[tid] = s0;
        if (a.net > 1) {
            float s1 = 0.f;
            for (int cc = 0; cc < 16; ++cc)
                s1 += a.Wd1[k * 64 + h2 * 16 + cc] * a.ad1[h2 * 16 + cc];
            We1[tid] = s1;
        }
    }
    __syncthreads();
    int wid = tid >> 6, c = tid & 63, hh = c >> 4;
    float b0c = a.b0[c];
    float b1c = (a.net > 1) ? a.b1[c] : 0.f;
    float gc = a.g[c], bbc = a.bb[c];
    int base = blockIdx.x * 16;
    for (int r = 0; r < 4; ++r) {
        int n = base + r * 4 + wid;
        if (n >= a.N) continue;
        size_t i64 = (size_t)n * 64 + c;
        float hrow = b2f(a.h[i64]);
        float x = hrow + b0c + b1c;
        x += gat_side(n, c, hh, hrow, We0, a.rp0, a.cols0, a.hs0, a.als0);
        if (a.net > 1)
            x += gat_side(n, c, hh, hrow, We1, a.rp1, a.cols1, a.hs1, a.als1);
        float s = x;
#pragma unroll
        for (int off = 32; off >= 1; off >>= 1) s += __shfl_xor(s, off, 64);
        float mu = s * (1.f / 64.f);
        float dlt = x - mu;
        float v2 = dlt * dlt;
#pragma unroll
        for (int off = 32; off >= 1; off >>= 1) v2 += __shfl_xor(v2, off, 64);
        float y = dlt * rsqrtf(v2 * (1.f / 64.f) + 1e-5f) * gc + bbc;
        y = fmaxf(y, 0.f);
        if (!a.last) a.h[i64] = f2b(y);
        else {
            if (*a.flag) ((float*)a.out)[a.obase + i64] = y;
            else         ((__hip_bfloat16*)a.out)[a.obase + i64] = f2b(y);
        }
    }
}

extern "C" void kernel_launch(void* const* d_in, const int* in_sizes, int n_in,
                              void* d_out, int out_size, void* d_ws, size_t ws_size,
                              hipStream_t stream)
{
    (void)n_in; (void)out_size; (void)ws_size;
    char* ws = (char*)d_ws;
    int* flag = (int*)ws;
    float* params = (float*)(ws + 256);

    size_t off[17]; off[0] = 0;
    for (int i = 0; i < 16; ++i) off[i + 1] = off[i] + (size_t)in_sizes[i];

    const float* Wi = params + off[3]; const float* bi = params + off[4];
    const float* Wq = params + off[5]; const float* bq = params + off[6];
    const float* Wt = params + off[7]; const float* bt = params + off[8];
    const float* Wsrc = params + off[9];
    const float* Wdst = params + off[10];
    const float* asrc = params + off[11];
    const float* adst = params + off[12];
    const float* cbias = params + off[13];
    const float* lng = params + off[14];
    const float* lnb = params + off[15];

    const int* ei[5];
    for (int j = 0; j < 5; ++j) ei[j] = (const int*)d_in[16 + j];

    __hip_bfloat16* h   = (__hip_bfloat16*)(ws + 7600000);
    __hip_bfloat16* h_i = h;
    __hip_bfloat16* h_q = h + (size_t)NI * 64;
    __hip_bfloat16* h_t = h + (size_t)(NI + NQ) * 64;
    __hip_bfloat16* hs_all = (__hip_bfloat16*)(ws + 39600000);
    float* als_all = (float*)(ws + 97200000);
    const size_t rowbase[5] = { 0, 100000, 200000, 300000, 400000 };

    const size_t RPS = 400032;
    int* rowptr[5]; int* cursor[5]; int* cols[5];
    for (int j = 0; j < 5; ++j) {
        rowptr[j] = (int*)(ws + 104400000 + j * RPS);
        cursor[j] = (int*)(ws + 106400320 + j * RPS);
        cols[j]   = (int*)(ws + 108400480 + (size_t)j * 2000000);
    }
    int* part = (int*)(ws + 118400480);

    // ---- dtype detect + widen PARAM tensors (3..15) only ----
    k_detect<<<1, 256, 0, stream>>>((const unsigned short*)d_in[0], flag);
    ConvArgs ca;
    for (int i = 0; i < 16; ++i) {
        ca.src[i] = d_in[i];
        ca.dst[i] = params + off[i];
        ca.n[i] = (i >= 3) ? in_sizes[i] : 0;   // features read directly
    }
    k_convert<<<dim3(160, 16), 256, 0, stream>>>(ca, flag);

    // ---- input projections (dtype-flag path) ----
    k_inproj<<<(NI + 3) / 4, 256, 0, stream>>>(d_in[0], NI, 8, Wi, bi, h_i, flag);
    k_inproj<<<(NQ + 3) / 4, 256, 0, stream>>>(d_in[1], NQ, 6, Wq, bq, h_q, flag);
    k_inproj<<<(NT + 3) / 4, 256, 0, stream>>>(d_in[2], NT, 8, Wt, bt, h_t, flag);

    // ---- counting sort of each edge list by dst (reused by both layers) ----
    const int Ndst_of[5] = { NI, NQ, NI, NT, NQ };
    for (int j = 0; j < 5; ++j) {
        int n = Ndst_of[j] + 1;
        int nb = (n + 255) / 256;
        hipMemsetAsync(rowptr[j], 0, (size_t)n * 4, stream);
        k_hist<<<(NE + 255) / 256, 256, 0, stream>>>(ei[j], NE, rowptr[j]);
        k_scan_block<<<nb, 256, 0, stream>>>(rowptr[j], n, part);
        k_scan_part<<<1, 512, 0, stream>>>(part, nb);
        k_scan_add<<<nb, 256, 0, stream>>>(rowptr[j], n, part);
        hipMemcpyAsync(cursor[j], rowptr[j], (size_t)n * 4, hipMemcpyDeviceToDevice, stream);
        k_scatter<<<(NE + 255) / 256, 256, 0, stream>>>(ei[j], NE, cursor[j], cols[j]);
    }

    const __hip_bfloat16* hsrc_of[5] = { h_i, h_i, h_q, h_q, h_t };

    for (int l = 0; l < 2; ++l) {
        TfArgs ta;
        for (int j = 0; j < 5; ++j) {
            ta.hsrc[j] = hsrc_of[j];
            ta.W[j] = Wsrc + (size_t)(l * 5 + j) * 4096;
            ta.avec[j] = asrc + (l * 5 + j) * 64;
            ta.hs[j] = hs_all + rowbase[j] * 64;
            ta.als[j] = als_all + rowbase[j] * 4;
        }
        k_transform_all<<<450000 / 16, 256, 0, stream>>>(ta);

        int last = (l == 1);
        auto dst_args = [&](__hip_bfloat16* hd, int N, int j0, int j1, int lnidx,
                            size_t obase) {
            DstArgs da;
            da.h = hd; da.N = N; da.net = (j1 >= 0) ? 2 : 1; da.last = last;
            da.rp0 = rowptr[j0]; da.cols0 = cols[j0];
            da.hs0 = hs_all + rowbase[j0] * 64; da.als0 = als_all + rowbase[j0] * 4;
            da.Wd0 = Wdst + (size_t)(l * 5 + j0) * 4096;
            da.ad0 = adst + (l * 5 + j0) * 64;
            da.b0 = cbias + (size_t)(l * 5 + j0) * 64;
            int jj = (j1 >= 0) ? j1 : j0;
            da.rp1 = rowptr[jj]; da.cols1 = cols[jj];
            da.hs1 = hs_all + rowbase[jj] * 64; da.als1 = als_all + rowbase[jj] * 4;
            da.Wd1 = Wdst + (size_t)(l * 5 + jj) * 4096;
            da.ad1 = adst + (l * 5 + jj) * 64;
            da.b1 = cbias + (size_t)(l * 5 + jj) * 64;
            da.g = lng + (size_t)(l * 3 + lnidx) * 64;
            da.bb = lnb + (size_t)(l * 3 + lnidx) * 64;
            da.out = d_out; da.obase = obase; da.flag = flag;
            return da;
        };
        k_dst<<<NI / 16, 256, 0, stream>>>(dst_args(h_i, NI, 0, 2, 0, 0));
        k_dst<<<NQ / 16, 256, 0, stream>>>(dst_args(h_q, NQ, 1, 4, 1, (size_t)NI * 64));
        k_dst<<<NT / 16, 256, 0, stream>>>(dst_args(h_t, NT, 3, -1, 2, (size_t)(NI + NQ) * 64));
    }
}

// Round 6
// 998.751 us; speedup vs baseline: 2.1868x; 1.1179x over previous
//
#include <hip/hip_runtime.h>
#include <hip/hip_bf16.h>
#include <cstddef>

// MCSHeteroGNN: 2-layer hetero GAT, CSR-gather, register-resident transforms.
// Node types: idle(100k), quasi(100k), task(50k). 5 edge types x 500k edges.
//
// ws layout (bytes), total ~118.5 MB:
//   flag    @ 0
//   params  @ 256         (f32 widened params; feature slots unused)
//   h  bf16 @ 7,600,000   (32,000,000) [idle|quasi|task]
//   hs bf16 @ 39,600,000  (57,600,000) [450k x 64]
//   als f32 @ 97,200,000  ( 7,200,000) [450k x 4]
//   rowptr  @104,400,000  (5 x 400,032)
//   cursor  @106,400,320  (5 x 400,032)
//   cols    @108,400,480  (5 x 2,000,000)
//   part    @118,400,480  (5 x 2,048)

static constexpr int NI = 100000, NQ = 100000, NT = 50000, NE = 500000;

__device__ __forceinline__ float b2f(__hip_bfloat16 x) { return __bfloat162float(x); }
__device__ __forceinline__ __hip_bfloat16 f2b(float x) { return __float2bfloat16(x); }

__global__ void k_detect(const unsigned short* __restrict__ x, int* __restrict__ flag)
{
    __shared__ int sh[256];
    int tid = threadIdx.x;
    int sane = 0;
    for (int i = tid * 2; i < 2048; i += 512) {
        unsigned short h = x[i];
        int e = (h >> 7) & 0xFF;
        if (h == 0 || (e >= 100 && e <= 140)) sane++;
    }
    sh[tid] = sane;
    __syncthreads();
    for (int s = 128; s; s >>= 1) { if (tid < s) sh[tid] += sh[tid + s]; __syncthreads(); }
    if (tid == 0) *flag = (sh[0] < 512) ? 1 : 0;   // 1 = buffers are f32
}

struct ConvArgs { const void* src[16]; float* dst[16]; int n[16]; };

__global__ void k_convert(ConvArgs a, const int* __restrict__ flag)
{
    int t = blockIdx.y;
    int i = blockIdx.x * 256 + threadIdx.x;
    if (i >= a.n[t]) return;
    float v = (*flag) ? ((const float*)a.src[t])[i]
                      : b2f(((const __hip_bfloat16*)a.src[t])[i]);
    a.dst[t][i] = v;
}

// ------------- input projection: h = relu(x @ W + b), dual-dtype -----------
__global__ void k_inproj(const void* __restrict__ xv, int N, int F,
                         const float* __restrict__ W, const float* __restrict__ b,
                         __hip_bfloat16* __restrict__ h, const int* __restrict__ flag)
{
    __shared__ float Wsh[8 * 64];
    __shared__ float bsh[64];
    int tid = threadIdx.x;
    for (int i = tid; i < F * 64; i += 256) Wsh[i] = W[i];
    if (tid < 64) bsh[tid] = b[tid];
    __syncthreads();
    int col = tid & 63;
    int n = blockIdx.x * 4 + (tid >> 6);
    if (n >= N) return;
    float acc = bsh[col];
    if (*flag) {
        const float* xr = (const float*)xv + (size_t)n * F;
        for (int k = 0; k < F; ++k) acc += xr[k] * Wsh[k * 64 + col];
    } else {
        const __hip_bfloat16* xr = (const __hip_bfloat16*)xv + (size_t)n * F;
        for (int k = 0; k < F; ++k) acc += b2f(xr[k]) * Wsh[k * 64 + col];
    }
    h[(size_t)n * 64 + col] = f2b(fmaxf(acc, 0.f));
}

// ---- all 5 etypes' hs = h_src @ Wsrc + als; W in VGPRs, h via readlane ----
struct TfArgs {
    const __hip_bfloat16* hsrc[5];
    const float* W[5];
    const float* avec[5];
    __hip_bfloat16* hs[5];
    float* als[5];
};
__global__ void __launch_bounds__(256) k_transform_all(TfArgs a)
{
    int tid = threadIdx.x;
    int c = tid & 63, wid = tid >> 6;
    int base = blockIdx.x * 80;               // 80 rows/block; 80 | 100000
    int j = base / 100000;
    const float* W = a.W[j];
    float wreg[64];
#pragma unroll
    for (int k = 0; k < 64; ++k) wreg[k] = W[k * 64 + c];
    float ac = a.avec[j][c];
    int nl0 = base - j * 100000 + wid * 20;
    const __hip_bfloat16* hsrc = a.hsrc[j];
    __hip_bfloat16* hs = a.hs[j];
    float* als = a.als[j];
    for (int r = 0; r < 20; ++r) {
        int nl = nl0 + r;
        float hv = b2f(hsrc[(size_t)nl * 64 + c]);
        int hb = __float_as_int(hv);
        float a0 = 0.f, a1 = 0.f, a2 = 0.f, a3 = 0.f;
#pragma unroll
        for (int k = 0; k < 64; k += 4) {
            float h0 = __int_as_float(__builtin_amdgcn_readlane(hb, k));
            float h1 = __int_as_float(__builtin_amdgcn_readlane(hb, k + 1));
            float h2 = __int_as_float(__builtin_amdgcn_readlane(hb, k + 2));
            float h3 = __int_as_float(__builtin_amdgcn_readlane(hb, k + 3));
            a0 = fmaf(h0, wreg[k], a0);
            a1 = fmaf(h1, wreg[k + 1], a1);
            a2 = fmaf(h2, wreg[k + 2], a2);
            a3 = fmaf(h3, wreg[k + 3], a3);
        }
        float acc = (a0 + a1) + (a2 + a3);
        hs[(size_t)nl * 64 + c] = f2b(acc);
        float p = acc * ac;
        p += __shfl_xor(p, 8, 16);
        p += __shfl_xor(p, 4, 16);
        p += __shfl_xor(p, 2, 16);
        p += __shfl_xor(p, 1, 16);
        if ((c & 15) == 0) als[(size_t)nl * 4 + (c >> 4)] = p;
    }
}

// ------------------- batched counting sort by dst (5 etypes) ---------------
struct SortArgs {
    const int* ei[5]; int* rowptr[5]; int* cursor[5]; int* cols[5]; int* part[5];
    int n[5];   // Ndst+1
};
__global__ void k_hist5(SortArgs s)
{
    int j = blockIdx.y;
    int e = blockIdx.x * 256 + threadIdx.x;
    if (e >= NE) return;
    atomicAdd(&s.rowptr[j][s.ei[j][NE + e] + 1], 1);
}
__global__ void k_scanb5(SortArgs s)
{
    __shared__ int sh[256];
    int j = blockIdx.y;
    int* a = s.rowptr[j];
    int n = s.n[j];
    int tid = threadIdx.x;
    int i = blockIdx.x * 256 + tid;
    int v = (i < n) ? a[i] : 0;
    sh[tid] = v; __syncthreads();
    for (int off = 1; off < 256; off <<= 1) {
        int t = (tid >= off) ? sh[tid - off] : 0;
        __syncthreads();
        sh[tid] += t;
        __syncthreads();
    }
    if (i < n) a[i] = sh[tid];
    if (tid == 255) s.part[j][blockIdx.x] = sh[255];
}
__global__ void k_scanp5(SortArgs s)
{
    __shared__ int sh[512];
    int j = blockIdx.x;
    int* part = s.part[j];
    int tid = threadIdx.x;
    int v = (tid < 391) ? part[tid] : 0;
    sh[tid] = v; __syncthreads();
    for (int off = 1; off < 512; off <<= 1) {
        int t = (tid >= off) ? sh[tid - off] : 0;
        __syncthreads();
        sh[tid] += t;
        __syncthreads();
    }
    if (tid < 391) part[tid] = sh[tid] - v;    // exclusive
}
__global__ void k_scana5(SortArgs s)
{
    int j = blockIdx.y;
    int i = blockIdx.x * 256 + threadIdx.x;
    if (i < s.n[j]) s.rowptr[j][i] += s.part[j][blockIdx.x];
}
__global__ void k_scatter5(SortArgs s)
{
    int j = blockIdx.y;
    int e = blockIdx.x * 256 + threadIdx.x;
    if (e >= NE) return;
    const int* ei = s.ei[j];
    int src = ei[e], d = ei[NE + e];
    int pos = atomicAdd(&s.cursor[j][d], 1);
    s.cols[j][pos] = src;
}

// ------------------ fused per-dst GAT gather + LN + ReLU -------------------
__device__ __forceinline__ float gat_side(int n, int c, int hh, float hrow,
    const float* We, const int* __restrict__ rp, const int* __restrict__ cols,
    const __hip_bfloat16* __restrict__ hs, const float* __restrict__ als)
{
    float aldv = 0.f;
#pragma unroll
    for (int hp = 0; hp < 4; ++hp) {
        float v = hrow * We[c * 4 + hp];
        v += __shfl_xor(v, 32, 64);
        v += __shfl_xor(v, 16, 64);
        v += __shfl_xor(v, 8, 64);
        v += __shfl_xor(v, 4, 64);
        v += __shfl_xor(v, 2, 64);
        v += __shfl_xor(v, 1, 64);
        if (hh == hp) aldv = v;
    }
    float acc = 0.f, den = 0.f;
    int beg = rp[n], end = rp[n + 1];
    // predicated 8-deep pipeline: 8 independent gathers in flight per step
    for (int e = beg; e < end; e += 8) {
        int idx[8];
#pragma unroll
        for (int u = 0; u < 8; ++u) {
            int ee = e + u;
            idx[u] = cols[(ee < end) ? ee : beg];
        }
        float av[8], gv[8];
#pragma unroll
        for (int u = 0; u < 8; ++u) av[u] = als[(size_t)idx[u] * 4 + hh];
#pragma unroll
        for (int u = 0; u < 8; ++u) gv[u] = b2f(hs[(size_t)idx[u] * 64 + c]);
#pragma unroll
        for (int u = 0; u < 8; ++u) {
            float al = av[u] + aldv;
            al = (al > 0.f) ? al : 0.2f * al;
            float w = __expf(fminf(al, 60.f));
            w = (e + u < end) ? w : 0.f;
            acc = fmaf(w, gv[u], acc);
            den += w;
        }
    }
    return acc / (den + 1e-16f);
}

struct DstArgs {
    __hip_bfloat16* h; int net; int last; int pad;
    const int* rp0; const int* cols0; const __hip_bfloat16* hs0; const float* als0;
    const float* Wd0; const float* ad0; const float* b0;
    const int* rp1; const int* cols1; const __hip_bfloat16* hs1; const float* als1;
    const float* Wd1; const float* ad1; const float* b1;
    const float* g; const float* bb;
    void* out; size_t obase; const int* flag;
};
struct DstAll { DstArgs a[3]; int blkoff[4]; };

__global__ void k_dst(DstAll all)
{
    int bid = blockIdx.x;
    int t = (bid >= all.blkoff[1]) + (bid >= all.blkoff[2]);
    const DstArgs& a = all.a[t];
    __shared__ float We0[256], We1[256];
    int tid = threadIdx.x;
    {
        int k = tid >> 2, h2 = tid & 3;
        float s0 = 0.f;
        for (int cc = 0; cc < 16; ++cc)
            s0 += a.Wd0[k * 64 + h2 * 16 + cc] * a.ad0[h2 * 16 + cc];
        We0[tid] = s0;
        if (a.net > 1) {
            float s1 = 0.f;
            for (int cc = 0; cc < 16; ++cc)
                s1 += a.Wd1[k * 64 + h2 * 16 + cc] * a.ad1[h2 * 16 + cc];
            We1[tid] = s1;
        }
    }
    __syncthreads();
    int wid = tid >> 6, c = tid & 63, hh = c >> 4;
    float b0c = a.b0[c];
    float b1c = (a.net > 1) ? a.b1[c] : 0.f;
    float gc = a.g[c], bbc = a.bb[c];
    int base = (bid - all.blkoff[t]) * 16;    // 16 nodes/block
    for (int r = 0; r < 4; ++r) {
        int n = base + r * 4 + wid;
        size_t i64 = (size_t)n * 64 + c;
        float hrow = b2f(a.h[i64]);
        float x = hrow + b0c + b1c;
        x += gat_side(n, c, hh, hrow, We0, a.rp0, a.cols0, a.hs0, a.als0);
        if (a.net > 1)
            x += gat_side(n, c, hh, hrow, We1, a.rp1, a.cols1, a.hs1, a.als1);
        float s = x;
#pragma unroll
        for (int off = 32; off >= 1; off >>= 1) s += __shfl_xor(s, off, 64);
        float mu = s * (1.f / 64.f);
        float dlt = x - mu;
        float v2 = dlt * dlt;
#pragma unroll
        for (int off = 32; off >= 1; off >>= 1) v2 += __shfl_xor(v2, off, 64);
        float y = dlt * rsqrtf(v2 * (1.f / 64.f) + 1e-5f) * gc + bbc;
        y = fmaxf(y, 0.f);
        if (!a.last) a.h[i64] = f2b(y);
        else {
            if (*a.flag) ((float*)a.out)[a.obase + i64] = y;
            else         ((__hip_bfloat16*)a.out)[a.obase + i64] = f2b(y);
        }
    }
}

extern "C" void kernel_launch(void* const* d_in, const int* in_sizes, int n_in,
                              void* d_out, int out_size, void* d_ws, size_t ws_size,
                              hipStream_t stream)
{
    (void)n_in; (void)out_size; (void)ws_size;
    char* ws = (char*)d_ws;
    int* flag = (int*)ws;
    float* params = (float*)(ws + 256);

    size_t off[17]; off[0] = 0;
    for (int i = 0; i < 16; ++i) off[i + 1] = off[i] + (size_t)in_sizes[i];

    const float* Wi = params + off[3]; const float* bi = params + off[4];
    const float* Wq = params + off[5]; const float* bq = params + off[6];
    const float* Wt = params + off[7]; const float* bt = params + off[8];
    const float* Wsrc = params + off[9];
    const float* Wdst = params + off[10];
    const float* asrc = params + off[11];
    const float* adst = params + off[12];
    const float* cbias = params + off[13];
    const float* lng = params + off[14];
    const float* lnb = params + off[15];

    __hip_bfloat16* h   = (__hip_bfloat16*)(ws + 7600000);
    __hip_bfloat16* h_i = h;
    __hip_bfloat16* h_q = h + (size_t)NI * 64;
    __hip_bfloat16* h_t = h + (size_t)(NI + NQ) * 64;
    __hip_bfloat16* hs_all = (__hip_bfloat16*)(ws + 39600000);
    float* als_all = (float*)(ws + 97200000);
    const size_t rowbase[5] = { 0, 100000, 200000, 300000, 400000 };

    const size_t RPS = 400032;
    SortArgs sa;
    const int Ndst_of[5] = { NI, NQ, NI, NT, NQ };
    for (int j = 0; j < 5; ++j) {
        sa.ei[j]     = (const int*)d_in[16 + j];
        sa.rowptr[j] = (int*)(ws + 104400000 + j * RPS);
        sa.cursor[j] = (int*)(ws + 106400320 + j * RPS);
        sa.cols[j]   = (int*)(ws + 108400480 + (size_t)j * 2000000);
        sa.part[j]   = (int*)(ws + 118400480 + j * 2048);
        sa.n[j]      = Ndst_of[j] + 1;
    }

    // ---- dtype detect + widen PARAM tensors (3..15) only ----
    k_detect<<<1, 256, 0, stream>>>((const unsigned short*)d_in[0], flag);
    ConvArgs ca;
    for (int i = 0; i < 16; ++i) {
        ca.src[i] = d_in[i];
        ca.dst[i] = params + off[i];
        ca.n[i] = (i >= 3) ? in_sizes[i] : 0;
    }
    k_convert<<<dim3(160, 16), 256, 0, stream>>>(ca, flag);

    // ---- input projections ----
    k_inproj<<<(NI + 3) / 4, 256, 0, stream>>>(d_in[0], NI, 8, Wi, bi, h_i, flag);
    k_inproj<<<(NQ + 3) / 4, 256, 0, stream>>>(d_in[1], NQ, 6, Wq, bq, h_q, flag);
    k_inproj<<<(NT + 3) / 4, 256, 0, stream>>>(d_in[2], NT, 8, Wt, bt, h_t, flag);

    // ---- batched counting sort (reused by both layers) ----
    hipMemsetAsync(ws + 104400000, 0, 5 * RPS, stream);
    k_hist5<<<dim3((NE + 255) / 256, 5), 256, 0, stream>>>(sa);
    k_scanb5<<<dim3(391, 5), 256, 0, stream>>>(sa);
    k_scanp5<<<5, 512, 0, stream>>>(sa);
    k_scana5<<<dim3(391, 5), 256, 0, stream>>>(sa);
    hipMemcpyAsync(ws + 106400320, ws + 104400000, 5 * RPS, hipMemcpyDeviceToDevice, stream);
    k_scatter5<<<dim3((NE + 255) / 256, 5), 256, 0, stream>>>(sa);

    const __hip_bfloat16* hsrc_of[5] = { h_i, h_i, h_q, h_q, h_t };

    for (int l = 0; l < 2; ++l) {
        TfArgs ta;
        for (int j = 0; j < 5; ++j) {
            ta.hsrc[j] = hsrc_of[j];
            ta.W[j] = Wsrc + (size_t)(l * 5 + j) * 4096;
            ta.avec[j] = asrc + (l * 5 + j) * 64;
            ta.hs[j] = hs_all + rowbase[j] * 64;
            ta.als[j] = als_all + rowbase[j] * 4;
        }
        k_transform_all<<<450000 / 80, 256, 0, stream>>>(ta);

        int last = (l == 1);
        DstAll da;
        da.blkoff[0] = 0; da.blkoff[1] = NI / 16;
        da.blkoff[2] = NI / 16 + NQ / 16; da.blkoff[3] = NI / 16 + NQ / 16 + NT / 16;
        struct Spec { __hip_bfloat16* hd; int j0, j1, lnidx; size_t obase; };
        Spec sp[3] = {
            { h_i, 0, 2, 0, 0 },
            { h_q, 1, 4, 1, (size_t)NI * 64 },
            { h_t, 3, -1, 2, (size_t)(NI + NQ) * 64 },
        };
        for (int t = 0; t < 3; ++t) {
            DstArgs& dd = da.a[t];
            dd.h = sp[t].hd; dd.net = (sp[t].j1 >= 0) ? 2 : 1; dd.last = last; dd.pad = 0;
            int j0 = sp[t].j0;
            dd.rp0 = sa.rowptr[j0]; dd.cols0 = sa.cols[j0];
            dd.hs0 = hs_all + rowbase[j0] * 64; dd.als0 = als_all + rowbase[j0] * 4;
            dd.Wd0 = Wdst + (size_t)(l * 5 + j0) * 4096;
            dd.ad0 = adst + (l * 5 + j0) * 64;
            dd.b0 = cbias + (size_t)(l * 5 + j0) * 64;
            int jj = (sp[t].j1 >= 0) ? sp[t].j1 : j0;
            dd.rp1 = sa.rowptr[jj]; dd.cols1 = sa.cols[jj];
            dd.hs1 = hs_all + rowbase[jj] * 64; dd.als1 = als_all + rowbase[jj] * 4;
            dd.Wd1 = Wdst + (size_t)(l * 5 + jj) * 4096;
            dd.ad1 = adst + (l * 5 + jj) * 64;
            dd.b1 = cbias + (size_t)(l * 5 + jj) * 64;
            dd.g = lng + (size_t)(l * 3 + sp[t].lnidx) * 64;
            dd.bb = lnb + (size_t)(l * 3 + sp[t].lnidx) * 64;
            dd.out = d_out; dd.obase = sp[t].obase; dd.flag = flag;
        }
        k_dst<<<da.blkoff[3], 256, 0, stream>>>(da);
    }
}